// Round 1
// 795.578 us; speedup vs baseline: 1.0001x; 1.0001x over previous
//
#include <hip/hip_runtime.h>
#include <hip/hip_bf16.h>

// Problem dims (fixed by reference)
#define B_  256
#define T_  250
#define D_  700
#define H_  1024
#define O_  20
#define KP  704          // K padded to multiple of 32 (22 K-steps of BK=32)
#define M_  64000        // B_*T_
#define NT  22           // K-tiles of BK=32

typedef __attribute__((ext_vector_type(8))) short bf16x8;
typedef __attribute__((ext_vector_type(4))) float f32x4;

// async global->LDS, 16B per lane (LDS dest = wave-uniform base + lane*16)
__device__ __forceinline__ void gl_lds16(const void* g, void* l) {
    __builtin_amdgcn_global_load_lds(
        (const __attribute__((address_space(1))) unsigned int*)g,
        (__attribute__((address_space(3))) unsigned int*)l, 16, 0, 0);
}

// ---------------------------------------------------------------------------
// Kernel A: split fp32 -> bf16 hi/lo, zero-padding K from Kin to Kout.
// ---------------------------------------------------------------------------
__global__ void split_convert(const float* __restrict__ src,
                              unsigned short* __restrict__ hi,
                              unsigned short* __restrict__ lo,
                              int M, int Kin, int Kout)
{
    int idx = blockIdx.x * blockDim.x + threadIdx.x;
    int chunks = Kout >> 3;
    int total = M * chunks;
    if (idx >= total) return;
    int m  = idx / chunks;
    int c  = idx - m * chunks;
    int d0 = c << 3;
    float x[8];
    if (d0 + 8 <= Kin) {
        const float4* p = (const float4*)(src + (long)m * Kin + d0);
        float4 v0 = p[0], v1 = p[1];
        x[0] = v0.x; x[1] = v0.y; x[2] = v0.z; x[3] = v0.w;
        x[4] = v1.x; x[5] = v1.y; x[6] = v1.z; x[7] = v1.w;
    } else {
#pragma unroll
        for (int e = 0; e < 8; ++e) {
            int d = d0 + e;
            x[e] = (d < Kin) ? src[(long)m * Kin + d] : 0.0f;
        }
    }
    unsigned short h8[8], l8[8];
#pragma unroll
    for (int e = 0; e < 8; ++e) {
        __hip_bfloat16 h = __float2bfloat16(x[e]);
        float hf = __bfloat162float(h);
        __hip_bfloat16 lv = __float2bfloat16(x[e] - hf);
        h8[e] = *(unsigned short*)&h;
        l8[e] = *(unsigned short*)&lv;
    }
    long ob = (long)m * Kout + d0;
    *(uint4*)(hi + ob) = *(uint4*)h8;
    *(uint4*)(lo + ob) = *(uint4*)l8;
}

// ---------------------------------------------------------------------------
// Kernel B: split-bf16 GEMM, 256x256 tile, 8 waves, phased schedule.
// Round-6 change: port from 128^2 single-buffer (m97-structure, ~900 TF
// ceiling) to the 256^2 multi-phase template (T1+T2+T3/T4+T5):
//   - BK=32, 4 LDS arrays (Ahi,Alo,Bhi,Blo), double-buffered = 128 KB LDS.
//   - 4 phases per K-tile: {ds_read 2 A-frag-pairs (+8 B-frags in ph0),
//     issue prefetch gl_lds (ph0/ph1), s_barrier, lgkmcnt(0), setprio(1),
//     24 MFMA, setprio(0), s_barrier}. vmcnt(0) only once per K-tile at
//     end of phase 3 -> ~3 phases of MFMA cover the prefetch latency.
//   - T2 XOR swizzle: physical 16B slot = logical slot ^ ((row>>1)&3).
//     gl_lds dest is linear; the XOR is pre-applied to the per-lane global
//     SOURCE address and re-applied on the ds_read address (involution).
//     Fragment reads drop from ~8-way to 2-way (free) bank aliasing.
//   - T1 bijective XCD swizzle (1000 blocks % 8 == 0).
// Accumulation math identical to round-5 (3-pass hh/hl/lh, same K order).
// ---------------------------------------------------------------------------
#define MF(a,b,c) (c) = __builtin_amdgcn_mfma_f32_16x16x32_bf16((a),(b),(c),0,0,0)

__global__ __launch_bounds__(512, 2) void gemm256(
    const unsigned short* __restrict__ Ahi, const unsigned short* __restrict__ Alo,
    const unsigned short* __restrict__ Bhi, const unsigned short* __restrict__ Blo,
    const float* __restrict__ bias, float* __restrict__ C)
{
    // 4 x 32 KB = 128 KB total, each [2 buf][256 rows][32 k] bf16
    __shared__ __align__(16) unsigned short sAh[2 * 8192];
    __shared__ __align__(16) unsigned short sAl[2 * 8192];
    __shared__ __align__(16) unsigned short sBh[2 * 8192];
    __shared__ __align__(16) unsigned short sBl[2 * 8192];

    // XCD-aware bijective swizzle: 1000 % 8 == 0 -> chunks of 125 per XCD
    const int bid = blockIdx.x;
    const int wg  = (bid & 7) * 125 + (bid >> 3);
    const int mblk = wg >> 2;        // 0..249
    const int nblk = wg & 3;         // 0..3

    const int t    = threadIdx.x;
    const int wave = t >> 6, lane = t & 63;
    const int wr = wave >> 2, wc = wave & 3;     // 2 (M) x 4 (N) waves

    // --- staging geometry: 16 chunks of 1 KB per array-tile, 2 per wave ---
    const int  ch0    = wave * 2;                       // chunks ch0, ch0+1
    const int  rowoff = lane >> 2;                      // 0..15 within chunk
    const int  slotl  = (lane & 3) ^ ((lane >> 3) & 3); // inverse-swizzled slot
    const long GCH    = 16L * KP;                       // global row step/chunk
    const long gArow  = (long)(mblk * 256 + rowoff) * KP + slotl * 8;
    const long gBrow  = (long)(nblk * 256 + rowoff) * KP + slotl * 8;
    const int  ldsl   = ch0 * 512 + lane * 8;           // ushort idx (linear)

    // --- fragment read offsets (swizzled) ---
    const int fr   = lane & 15, fq = lane >> 4;
    const int fxor = ((fq ^ ((fr >> 1) & 3)) << 3);
    const int abase = (wr * 128 + fr) * 32 + fxor;      // + i*512 + buf*8192
    const int bbase = (wc * 64 + fr) * 32 + fxor;       // + j*512 + buf*8192

    f32x4 acc[8][4];
#pragma unroll
    for (int i = 0; i < 8; ++i)
#pragma unroll
        for (int j = 0; j < 4; ++j) acc[i][j] = (f32x4){0.f, 0.f, 0.f, 0.f};

    // --- prologue: stage tile 0 into buffer 0 ---
    gl_lds16(Ahi + gArow + ch0 * GCH,       &sAh[ldsl]);
    gl_lds16(Ahi + gArow + (ch0 + 1) * GCH, &sAh[ldsl + 512]);
    gl_lds16(Bhi + gBrow + ch0 * GCH,       &sBh[ldsl]);
    gl_lds16(Bhi + gBrow + (ch0 + 1) * GCH, &sBh[ldsl + 512]);
    gl_lds16(Alo + gArow + ch0 * GCH,       &sAl[ldsl]);
    gl_lds16(Alo + gArow + (ch0 + 1) * GCH, &sAl[ldsl + 512]);
    gl_lds16(Blo + gBrow + ch0 * GCH,       &sBl[ldsl]);
    gl_lds16(Blo + gBrow + (ch0 + 1) * GCH, &sBl[ldsl + 512]);
    asm volatile("s_waitcnt vmcnt(0)" ::: "memory");
    __builtin_amdgcn_s_barrier();

    for (int tt = 0; tt < NT; ++tt) {
        const int  cur = (tt & 1) ? 8192 : 0;
        const int  nxt = 8192 - cur;
        const long ksn = (long)(tt + 1) * 32;   // next tile k-offset (elements)
        const bool pf  = (tt + 1 < NT);

        bf16x8 bh[4], bl[4];
#pragma unroll
        for (int p = 0; p < 4; ++p) {
            const int i0 = 2 * p, i1 = 2 * p + 1;
            // ds_reads for this phase (compiler tracks lgkmcnt deps)
            bf16x8 ah0 = *(const bf16x8*)&sAh[cur + abase + i0 * 512];
            bf16x8 ah1 = *(const bf16x8*)&sAh[cur + abase + i1 * 512];
            bf16x8 al0 = *(const bf16x8*)&sAl[cur + abase + i0 * 512];
            bf16x8 al1 = *(const bf16x8*)&sAl[cur + abase + i1 * 512];
            if (p == 0) {
#pragma unroll
                for (int j = 0; j < 4; ++j) {
                    bh[j] = *(const bf16x8*)&sBh[cur + bbase + j * 512];
                    bl[j] = *(const bf16x8*)&sBl[cur + bbase + j * 512];
                }
            }
            // prefetch next K-tile (all 8 loads issued across phases 0-1)
            if (p == 0 && pf) {
                gl_lds16(Ahi + gArow + ch0 * GCH + ksn,       &sAh[nxt + ldsl]);
                gl_lds16(Ahi + gArow + (ch0 + 1) * GCH + ksn, &sAh[nxt + ldsl + 512]);
                gl_lds16(Bhi + gBrow + ch0 * GCH + ksn,       &sBh[nxt + ldsl]);
                gl_lds16(Bhi + gBrow + (ch0 + 1) * GCH + ksn, &sBh[nxt + ldsl + 512]);
            }
            if (p == 1 && pf) {
                gl_lds16(Alo + gArow + ch0 * GCH + ksn,       &sAl[nxt + ldsl]);
                gl_lds16(Alo + gArow + (ch0 + 1) * GCH + ksn, &sAl[nxt + ldsl + 512]);
                gl_lds16(Blo + gBrow + ch0 * GCH + ksn,       &sBl[nxt + ldsl]);
                gl_lds16(Blo + gBrow + (ch0 + 1) * GCH + ksn, &sBl[nxt + ldsl + 512]);
            }
            __builtin_amdgcn_s_barrier();
            asm volatile("s_waitcnt lgkmcnt(0)" ::: "memory");
            __builtin_amdgcn_sched_barrier(0);
            __builtin_amdgcn_s_setprio(1);
            // 24 MFMA; per-acc reuse distance 8
#pragma unroll
            for (int j = 0; j < 4; ++j) MF(ah0, bh[j], acc[i0][j]);
#pragma unroll
            for (int j = 0; j < 4; ++j) MF(ah1, bh[j], acc[i1][j]);
#pragma unroll
            for (int j = 0; j < 4; ++j) MF(ah0, bl[j], acc[i0][j]);
#pragma unroll
            for (int j = 0; j < 4; ++j) MF(ah1, bl[j], acc[i1][j]);
#pragma unroll
            for (int j = 0; j < 4; ++j) MF(al0, bh[j], acc[i0][j]);
#pragma unroll
            for (int j = 0; j < 4; ++j) MF(al1, bh[j], acc[i1][j]);
            __builtin_amdgcn_s_setprio(0);
            if (p == 3) asm volatile("s_waitcnt vmcnt(0)" ::: "memory");
            __builtin_amdgcn_s_barrier();
        }
    }

    // --- epilogue ---
    const int r0 = mblk * 256 + wr * 128 + fq * 4;
    const int cc = nblk * 256 + wc * 64 + fr;
#pragma unroll
    for (int j = 0; j < 4; ++j) {
        int col = cc + j * 16;
        float bv = bias[col];
#pragma unroll
        for (int i = 0; i < 8; ++i) {
            int row = r0 + i * 16;
#pragma unroll
            for (int r = 0; r < 4; ++r)
                C[(long)(row + r) * H_ + col] = acc[i][j][r] + bv;
        }
    }
}

// ---------------------------------------------------------------------------
// Kernel C1: layer-1 LIF scan. Ring depth 6.
// ---------------------------------------------------------------------------
__global__ __launch_bounds__(256) void lif_spikes(
    const float* __restrict__ d1,    // [B*T, H]
    const float* __restrict__ tau1,
    unsigned long long* __restrict__ spk)  // [B*T, 16]
{
    const int b    = blockIdx.y;
    const int h    = blockIdx.x * 256 + threadIdx.x;
    const int lane = threadIdx.x & 63;
    const int widx = blockIdx.x * 4 + (threadIdx.x >> 6);

    float tv  = tau1[h];
    float a1  = 1.0f / (1.0f + __expf(-tv));
    float om1 = 1.0f - a1;
    float mem = 0.f, sp = 0.f;

    const float* dp = d1 + (long)b * T_ * H_ + h;
    unsigned long long* op = spk + (long)b * T_ * 16 + widx;

    float p0 = dp[0],        p1 = dp[1L * H_], p2 = dp[2L * H_];
    float p3 = dp[3L * H_],  p4 = dp[4L * H_], p5 = dp[5L * H_];

    for (int ts = 0; ts < T_; ++ts) {
        float cur = p0;
        p0 = p1; p1 = p2; p2 = p3; p3 = p4; p4 = p5;
        int nts = ts + 6; nts = (nts < T_) ? nts : (T_ - 1);
        p5 = dp[(long)nts * H_];

        mem = mem * a1 + om1 * cur - sp;
        sp  = (mem > 1.0f) ? 1.0f : 0.0f;
        unsigned long long msk = __ballot(mem > 1.0f);
        if (lane == 0) op[(long)ts * 16] = msk;
    }
}

// ---------------------------------------------------------------------------
// Kernel C2: d2 dots. 2000 blocks x 32 rows, 2-row ILP.
// ---------------------------------------------------------------------------
__global__ __launch_bounds__(256) void readout_dots(
    const unsigned long long* __restrict__ spk,  // [M_, 16]
    const float* __restrict__ W2,                // [O_, H_]
    float* __restrict__ d2t)                     // idx o*M_ + ts*256 + b
{
    const int t = threadIdx.x, wave = t >> 6, lane = t & 63;

    float w2r[5][16];
#pragma unroll
    for (int oo = 0; oo < 5; ++oo)
#pragma unroll
        for (int q = 0; q < 4; ++q)
            *(float4*)&w2r[oo][4 * q] =
                *(const float4*)&W2[(wave * 5 + oo) * H_ + lane * 16 + 4 * q];

    const int rbase = blockIdx.x * 32;           // M_ = 2000*32
    int b0 = rbase / T_;
    int ts0 = rbase - b0 * T_;

    for (int i = 0; i < 32; i += 2) {
        int r0 = rbase + i, r1 = r0 + 1;
        unsigned long long bw0 = spk[(long)r0 * 16 + (lane >> 2)];
        unsigned long long bw1 = spk[(long)r1 * 16 + (lane >> 2)];
        unsigned int bits0 = (unsigned int)(bw0 >> ((lane & 3) * 16)) & 0xFFFFu;
        unsigned int bits1 = (unsigned int)(bw1 >> ((lane & 3) * 16)) & 0xFFFFu;
        float pa0[5] = {0, 0, 0, 0, 0}, pa1[5] = {0, 0, 0, 0, 0};
#pragma unroll
        for (int j = 0; j < 16; ++j) {
            float f0 = (bits0 >> j) & 1u ? 1.0f : 0.0f;
            float f1 = (bits1 >> j) & 1u ? 1.0f : 0.0f;
#pragma unroll
            for (int oo = 0; oo < 5; ++oo) {
                pa0[oo] = fmaf(f0, w2r[oo][j], pa0[oo]);
                pa1[oo] = fmaf(f1, w2r[oo][j], pa1[oo]);
            }
        }
#pragma unroll
        for (int m = 1; m < 64; m <<= 1)
#pragma unroll
            for (int oo = 0; oo < 5; ++oo) {
                pa0[oo] += __shfl_xor(pa0[oo], m, 64);
                pa1[oo] += __shfl_xor(pa1[oo], m, 64);
            }
        if (lane == 0) {
            int bA = b0, tsA = ts0 + i;
            if (tsA >= T_) { tsA -= T_; bA += 1; }   // rbase%2==0, i even: safe
            int bB = bA, tsB = tsA + 1;
            if (tsB >= T_) { tsB = 0; bB += 1; }
#pragma unroll
            for (int oo = 0; oo < 5; ++oo) {
                d2t[(long)(wave * 5 + oo) * M_ + tsA * 256 + bA] = pa0[oo];
                d2t[(long)(wave * 5 + oo) * M_ + tsB * 256 + bB] = pa1[oo];
            }
        }
    }
}

// ---------------------------------------------------------------------------
// Kernel C3: mem2 linear recurrence. grid (20 o x 4 b-chunks), 64 threads.
// ---------------------------------------------------------------------------
__global__ __launch_bounds__(64) void mem2_scan(
    const float* __restrict__ d2t,   // (o, ts, b)
    const float* __restrict__ tau2, const float* __restrict__ b2,
    float* __restrict__ m2t)         // (o, ts, b)
{
    const int o = blockIdx.x;                    // 0..19
    const int b = blockIdx.y * 64 + threadIdx.x; // 0..255
    float tv  = tau2[o];
    float a2  = 1.0f / (1.0f + __expf(-tv));
    float om2 = 1.0f - a2;
    float bv  = b2[o];

    const float* dp = d2t + (long)o * M_ + b;
    float*       mp = m2t + (long)o * M_ + b;
    float mem = 0.f;

    float p0 = dp[0], p1 = dp[256], p2 = dp[512], p3 = dp[768];
    for (int ts = 0; ts < T_; ++ts) {
        float cur = p0; p0 = p1; p1 = p2; p2 = p3;
        int nts = ts + 4; nts = (nts < T_) ? nts : (T_ - 1);
        p3 = dp[(long)nts * 256];
        mem = mem * a2 + om2 * (cur + bv);
        mp[(long)ts * 256] = mem;
    }
}

// ---------------------------------------------------------------------------
// Kernel C4: per-(b,ts) softmax in-register + per-b sum over ts via LDS.
// ---------------------------------------------------------------------------
__global__ __launch_bounds__(256) void softmax_acc(
    const float* __restrict__ m2t,   // (o, ts, b)
    float* __restrict__ out)         // [B_, O_]
{
    __shared__ float sp[T_][O_];     // 19.5 KB
    const int b  = blockIdx.x;
    const int ts = threadIdx.x;

    if (ts < T_) {
        if (ts > 10) {
            float m[O_];
#pragma unroll
            for (int o = 0; o < O_; ++o)
                m[o] = m2t[(long)o * M_ + ts * 256 + b];
            float mx = m[0];
#pragma unroll
            for (int o = 1; o < O_; ++o) mx = fmaxf(mx, m[o]);
            float s = 0.f;
#pragma unroll
            for (int o = 0; o < O_; ++o) { m[o] = __expf(m[o] - mx); s += m[o]; }
            float inv = 1.0f / s;
#pragma unroll
            for (int o = 0; o < O_; ++o) sp[ts][o] = m[o] * inv;
        } else {
#pragma unroll
            for (int o = 0; o < O_; ++o) sp[ts][o] = 0.f;
        }
    }
    __syncthreads();
    if (ts < O_) {
        float s = 0.f;
        for (int k = 11; k < T_; ++k) s += sp[k][ts];
        out[b * O_ + ts] = s;
    }
}

// ---------------------------------------------------------------------------
extern "C" void kernel_launch(void* const* d_in, const int* in_sizes, int n_in,
                              void* d_out, int out_size, void* d_ws, size_t ws_size,
                              hipStream_t stream)
{
    const float* X    = (const float*)d_in[0];
    const float* W1   = (const float*)d_in[1];
    const float* b1   = (const float*)d_in[2];
    const float* tau1 = (const float*)d_in[3];
    const float* W2   = (const float*)d_in[4];
    const float* b2   = (const float*)d_in[5];
    const float* tau2 = (const float*)d_in[6];
    float* out = (float*)d_out;

    unsigned short* Xhi  = (unsigned short*)d_ws;
    unsigned short* Xlo  = Xhi + (long)M_ * KP;
    unsigned short* W1hi = Xlo + (long)M_ * KP;
    unsigned short* W1lo = W1hi + (long)H_ * KP;
    float* d1 = (float*)(W1lo + (long)H_ * KP);  // [M_, H] fp32

    unsigned long long* spk = (unsigned long long*)Xhi;      // aliases X splits
    float* d2t = (float*)Xlo;                                // (safe: sequential)
    float* m2t = d2t + (long)O_ * M_;

    // 1. split conversions
    {
        int chunks = M_ * (KP / 8);
        split_convert<<<(chunks + 255) / 256, 256, 0, stream>>>(X, Xhi, Xlo, M_, D_, KP);
    }
    {
        int chunks = H_ * (KP / 8);
        split_convert<<<(chunks + 255) / 256, 256, 0, stream>>>(W1, W1hi, W1lo, H_, D_, KP);
    }

    // 2. d1 = X @ W1^T + b1  (256^2 tile, 1000 blocks = 250 m x 4 n)
    gemm256<<<dim3(1000), dim3(512), 0, stream>>>(Xhi, Xlo, W1hi, W1lo, b1, d1);

    // 3. layer-1 spike scan
    {
        dim3 grid(H_ / 256, B_);                 // (4, 256)
        lif_spikes<<<grid, 256, 0, stream>>>(d1, tau1, spk);
    }

    // 4. readout dots
    readout_dots<<<M_ / 32, 256, 0, stream>>>(spk, W2, d2t);

    // 5. mem2 linear scan
    {
        dim3 grid(O_, 4);
        mem2_scan<<<grid, 64, 0, stream>>>(d2t, tau2, b2, m2t);
    }

    // 6. softmax + accumulate
    softmax_acc<<<B_, 256, 0, stream>>>(m2t, out);
}

// Round 3
// 714.160 us; speedup vs baseline: 1.1142x; 1.1140x over previous
//
#include <hip/hip_runtime.h>
#include <hip/hip_bf16.h>

// Problem dims (fixed by reference)
#define B_  256
#define T_  250
#define D_  700
#define H_  1024
#define O_  20
#define KP  704          // K padded to multiple of 32 (22 K-steps of BK=32)
#define M_  64000        // B_*T_
#define NT  22           // K-tiles of BK=32

typedef __attribute__((ext_vector_type(8))) short bf16x8;
typedef __attribute__((ext_vector_type(4))) float f32x4;

// async global->LDS, 16B per lane (LDS dest = wave-uniform base + lane*16)
__device__ __forceinline__ void gl_lds16(const void* g, void* l) {
    __builtin_amdgcn_global_load_lds(
        (const __attribute__((address_space(1))) unsigned int*)g,
        (__attribute__((address_space(3))) unsigned int*)l, 16, 0, 0);
}

// ---------------------------------------------------------------------------
// Kernel A: split fp32 -> bf16 hi/lo, zero-padding K from Kin to Kout.
// ---------------------------------------------------------------------------
__global__ void split_convert(const float* __restrict__ src,
                              unsigned short* __restrict__ hi,
                              unsigned short* __restrict__ lo,
                              int M, int Kin, int Kout)
{
    int idx = blockIdx.x * blockDim.x + threadIdx.x;
    int chunks = Kout >> 3;
    int total = M * chunks;
    if (idx >= total) return;
    int m  = idx / chunks;
    int c  = idx - m * chunks;
    int d0 = c << 3;
    float x[8];
    if (d0 + 8 <= Kin) {
        const float4* p = (const float4*)(src + (long)m * Kin + d0);
        float4 v0 = p[0], v1 = p[1];
        x[0] = v0.x; x[1] = v0.y; x[2] = v0.z; x[3] = v0.w;
        x[4] = v1.x; x[5] = v1.y; x[6] = v1.z; x[7] = v1.w;
    } else {
#pragma unroll
        for (int e = 0; e < 8; ++e) {
            int d = d0 + e;
            x[e] = (d < Kin) ? src[(long)m * Kin + d] : 0.0f;
        }
    }
    unsigned short h8[8], l8[8];
#pragma unroll
    for (int e = 0; e < 8; ++e) {
        __hip_bfloat16 h = __float2bfloat16(x[e]);
        float hf = __bfloat162float(h);
        __hip_bfloat16 lv = __float2bfloat16(x[e] - hf);
        h8[e] = *(unsigned short*)&h;
        l8[e] = *(unsigned short*)&lv;
    }
    long ob = (long)m * Kout + d0;
    *(uint4*)(hi + ob) = *(uint4*)h8;
    *(uint4*)(lo + ob) = *(uint4*)l8;
}

// ---------------------------------------------------------------------------
// Kernel B: split-bf16 GEMM, 256x256 tile, 8 waves, 4-phase schedule with
// T4 derived counted vmem waits (m201/m218 scheme). Round-8: identical
// schedule to round-7 (which hit an infra failure, no counters); macros
// replaced by __forceinline__ functions as compile-risk hardening.
//   Per-wave staging groups, fixed in-order issue B(4),A0(2),A1(2)/tile:
//     B  = Bhi/Blo chunks 2w,2w+1            (needed ph0)
//     A0 = Ahi/Alo chunk (w<4 ? w   : w+4)   (rows 0-63,128-191; ph0-1)
//     A1 = cA0+4                             (rows 64-127,192-255; ph2-3)
//   ph0: vmcnt(2) [A1(t) stays in flight] + barrier; read B-frags+A(0,1);
//        issue B(t+1); lgkm0; 24 MFMA.
//   ph1: read A(2,3); issue A0(t+1); lgkm0; MFMA.
//   ph2: vmcnt(6) [B,A0(t+1) stay in flight] + barrier; read A(4,5);
//        issue A1(t+1); lgkm0; MFMA.
//   ph3: read A(6,7); lgkm0; MFMA.
//   => 2 barriers/K-tile, 6-8 loads always in flight, wait->use distance
//      >= 3 phases. Tail tile: vmcnt(0) at ph2.
// T1 (bijective XCD swizzle), T2 (XOR both-sides LDS swizzle, verified
// conflict-free: counter 2.25e7 -> 0 in round 1), T5 (setprio) kept.
// Accumulation math identical (3-pass hh/hl/lh, same K order).
// ---------------------------------------------------------------------------
#define MF(a,b,c) (c) = __builtin_amdgcn_mfma_f32_16x16x32_bf16((a),(b),(c),0,0,0)

__device__ __forceinline__ void phase_mfma(
    const bf16x8 ah0, const bf16x8 ah1, const bf16x8 al0, const bf16x8 al1,
    const bf16x8* bh, const bf16x8* bl, f32x4* acc0, f32x4* acc1)
{
    asm volatile("s_waitcnt lgkmcnt(0)" ::: "memory");
    __builtin_amdgcn_sched_barrier(0);
    __builtin_amdgcn_s_setprio(1);
#pragma unroll
    for (int j = 0; j < 4; ++j) MF(ah0, bh[j], acc0[j]);
#pragma unroll
    for (int j = 0; j < 4; ++j) MF(ah1, bh[j], acc1[j]);
#pragma unroll
    for (int j = 0; j < 4; ++j) MF(ah0, bl[j], acc0[j]);
#pragma unroll
    for (int j = 0; j < 4; ++j) MF(ah1, bl[j], acc1[j]);
#pragma unroll
    for (int j = 0; j < 4; ++j) MF(al0, bh[j], acc0[j]);
#pragma unroll
    for (int j = 0; j < 4; ++j) MF(al1, bh[j], acc1[j]);
    __builtin_amdgcn_s_setprio(0);
}

__global__ __launch_bounds__(512, 2) void gemm256(
    const unsigned short* __restrict__ Ahi, const unsigned short* __restrict__ Alo,
    const unsigned short* __restrict__ Bhi, const unsigned short* __restrict__ Blo,
    const float* __restrict__ bias, float* __restrict__ C)
{
    // 4 x 32 KB = 128 KB total, each [2 buf][256 rows][32 k] bf16
    __shared__ __align__(16) unsigned short sAh[2 * 8192];
    __shared__ __align__(16) unsigned short sAl[2 * 8192];
    __shared__ __align__(16) unsigned short sBh[2 * 8192];
    __shared__ __align__(16) unsigned short sBl[2 * 8192];

    // XCD-aware bijective swizzle: 1000 % 8 == 0 -> chunks of 125 per XCD
    const int bid = blockIdx.x;
    const int wg  = (bid & 7) * 125 + (bid >> 3);
    const int mblk = wg >> 2;        // 0..249
    const int nblk = wg & 3;         // 0..3

    const int t    = threadIdx.x;
    const int wave = t >> 6, lane = t & 63;
    const int wr = wave >> 2, wc = wave & 3;     // 2 (M) x 4 (N) waves

    // --- staging geometry: chunk = 16 rows x 32 k = 1 KB (one gl_lds16/wave)
    const int  rowoff = lane >> 2;                      // 0..15 within chunk
    const int  slotl  = (lane & 3) ^ ((lane >> 3) & 3); // inverse-swizzled slot
    const long GCH    = 16L * KP;                       // global row step/chunk
    const long gA     = (long)(mblk * 256 + rowoff) * KP + slotl * 8;
    const long gB     = (long)(nblk * 256 + rowoff) * KP + slotl * 8;
    const int  ldsO   = lane * 8;                       // + chunk*512 + buf
    // per-wave chunk assignment (issue groups)
    const int  cB0 = 2 * wave, cB1 = 2 * wave + 1;      // B chunks (ph0 need)
    const int  cA0 = (wave < 4) ? wave : wave + 4;      // A rows 0-63,128-191
    const int  cA1 = cA0 + 4;                           // A rows 64-127,192-255

    const unsigned short* gBh = Bhi + gB;
    const unsigned short* gBl = Blo + gB;
    const unsigned short* gAh = Ahi + gA;
    const unsigned short* gAl = Alo + gA;

    // issue groups as lambdas (fixed in-order issue sequence per tile)
    auto issueB = [&](long ko, int bufo) {
        gl_lds16(gBh + (long)cB0 * GCH + ko, &sBh[bufo + cB0 * 512 + ldsO]);
        gl_lds16(gBh + (long)cB1 * GCH + ko, &sBh[bufo + cB1 * 512 + ldsO]);
        gl_lds16(gBl + (long)cB0 * GCH + ko, &sBl[bufo + cB0 * 512 + ldsO]);
        gl_lds16(gBl + (long)cB1 * GCH + ko, &sBl[bufo + cB1 * 512 + ldsO]);
    };
    auto issueA0 = [&](long ko, int bufo) {
        gl_lds16(gAh + (long)cA0 * GCH + ko, &sAh[bufo + cA0 * 512 + ldsO]);
        gl_lds16(gAl + (long)cA0 * GCH + ko, &sAl[bufo + cA0 * 512 + ldsO]);
    };
    auto issueA1 = [&](long ko, int bufo) {
        gl_lds16(gAh + (long)cA1 * GCH + ko, &sAh[bufo + cA1 * 512 + ldsO]);
        gl_lds16(gAl + (long)cA1 * GCH + ko, &sAl[bufo + cA1 * 512 + ldsO]);
    };

    // --- fragment read offsets (swizzled; involution with slotl) ---
    const int fr   = lane & 15, fq = lane >> 4;
    const int fxor = ((fq ^ ((fr >> 1) & 3)) << 3);
    const int abase = (wr * 128 + fr) * 32 + fxor;      // + i*512 + buf
    const int bbase = (wc * 64 + fr) * 32 + fxor;       // + j*512 + buf

    f32x4 acc[8][4];
#pragma unroll
    for (int i = 0; i < 8; ++i)
#pragma unroll
        for (int j = 0; j < 4; ++j) acc[i][j] = (f32x4){0.f, 0.f, 0.f, 0.f};

    // --- prologue: stage tile 0 into buffer 0 (issue order B, A0, A1) ---
    issueB(0, 0); issueA0(0, 0); issueA1(0, 0);

    for (int tt = 0; tt < NT; ++tt) {
        const int  cur = (tt & 1) ? 8192 : 0;
        const int  nxt = 8192 - cur;
        const long ksn = (long)(tt + 1) * 32;   // next tile k-offset (elements)
        const bool pf  = (tt + 1 < NT);

        // ================= phase 0 =================
        // own B(t)+A0(t) done; A1(t) (2 newest) stays in flight
        asm volatile("s_waitcnt vmcnt(2)" ::: "memory");
        __builtin_amdgcn_s_barrier();
        bf16x8 bh[4], bl[4];
#pragma unroll
        for (int j = 0; j < 4; ++j) {
            bh[j] = *(const bf16x8*)&sBh[cur + bbase + j * 512];
            bl[j] = *(const bf16x8*)&sBl[cur + bbase + j * 512];
        }
        bf16x8 a0h = *(const bf16x8*)&sAh[cur + abase + 0 * 512];
        bf16x8 a1h = *(const bf16x8*)&sAh[cur + abase + 1 * 512];
        bf16x8 a0l = *(const bf16x8*)&sAl[cur + abase + 0 * 512];
        bf16x8 a1l = *(const bf16x8*)&sAl[cur + abase + 1 * 512];
        if (pf) issueB(ksn, nxt);
        phase_mfma(a0h, a1h, a0l, a1l, bh, bl, acc[0], acc[1]);

        // ================= phase 1 =================
        bf16x8 a2h = *(const bf16x8*)&sAh[cur + abase + 2 * 512];
        bf16x8 a3h = *(const bf16x8*)&sAh[cur + abase + 3 * 512];
        bf16x8 a2l = *(const bf16x8*)&sAl[cur + abase + 2 * 512];
        bf16x8 a3l = *(const bf16x8*)&sAl[cur + abase + 3 * 512];
        if (pf) issueA0(ksn, nxt);
        phase_mfma(a2h, a3h, a2l, a3l, bh, bl, acc[2], acc[3]);

        // ================= phase 2 =================
        // drain A1(t); leave B(t+1)+A0(t+1) = 6 in flight (tail: drain all)
        if (pf) { asm volatile("s_waitcnt vmcnt(6)" ::: "memory"); }
        else    { asm volatile("s_waitcnt vmcnt(0)" ::: "memory"); }
        __builtin_amdgcn_s_barrier();
        bf16x8 a4h = *(const bf16x8*)&sAh[cur + abase + 4 * 512];
        bf16x8 a5h = *(const bf16x8*)&sAh[cur + abase + 5 * 512];
        bf16x8 a4l = *(const bf16x8*)&sAl[cur + abase + 4 * 512];
        bf16x8 a5l = *(const bf16x8*)&sAl[cur + abase + 5 * 512];
        if (pf) issueA1(ksn, nxt);
        phase_mfma(a4h, a5h, a4l, a5l, bh, bl, acc[4], acc[5]);

        // ================= phase 3 =================
        bf16x8 a6h = *(const bf16x8*)&sAh[cur + abase + 6 * 512];
        bf16x8 a7h = *(const bf16x8*)&sAh[cur + abase + 7 * 512];
        bf16x8 a6l = *(const bf16x8*)&sAl[cur + abase + 6 * 512];
        bf16x8 a7l = *(const bf16x8*)&sAl[cur + abase + 7 * 512];
        phase_mfma(a6h, a7h, a6l, a7l, bh, bl, acc[6], acc[7]);
    }

    // --- epilogue ---
    const int r0 = mblk * 256 + wr * 128 + fq * 4;
    const int cc = nblk * 256 + wc * 64 + fr;
#pragma unroll
    for (int j = 0; j < 4; ++j) {
        int col = cc + j * 16;
        float bv = bias[col];
#pragma unroll
        for (int i = 0; i < 8; ++i) {
            int row = r0 + i * 16;
#pragma unroll
            for (int r = 0; r < 4; ++r)
                C[(long)(row + r) * H_ + col] = acc[i][j][r] + bv;
        }
    }
}

// ---------------------------------------------------------------------------
// Kernel C1: layer-1 LIF scan. Ring depth 6.
// ---------------------------------------------------------------------------
__global__ __launch_bounds__(256) void lif_spikes(
    const float* __restrict__ d1,    // [B*T, H]
    const float* __restrict__ tau1,
    unsigned long long* __restrict__ spk)  // [B*T, 16]
{
    const int b    = blockIdx.y;
    const int h    = blockIdx.x * 256 + threadIdx.x;
    const int lane = threadIdx.x & 63;
    const int widx = blockIdx.x * 4 + (threadIdx.x >> 6);

    float tv  = tau1[h];
    float a1  = 1.0f / (1.0f + __expf(-tv));
    float om1 = 1.0f - a1;
    float mem = 0.f, sp = 0.f;

    const float* dp = d1 + (long)b * T_ * H_ + h;
    unsigned long long* op = spk + (long)b * T_ * 16 + widx;

    float p0 = dp[0],        p1 = dp[1L * H_], p2 = dp[2L * H_];
    float p3 = dp[3L * H_],  p4 = dp[4L * H_], p5 = dp[5L * H_];

    for (int ts = 0; ts < T_; ++ts) {
        float cur = p0;
        p0 = p1; p1 = p2; p2 = p3; p3 = p4; p4 = p5;
        int nts = ts + 6; nts = (nts < T_) ? nts : (T_ - 1);
        p5 = dp[(long)nts * H_];

        mem = mem * a1 + om1 * cur - sp;
        sp  = (mem > 1.0f) ? 1.0f : 0.0f;
        unsigned long long msk = __ballot(mem > 1.0f);
        if (lane == 0) op[(long)ts * 16] = msk;
    }
}

// ---------------------------------------------------------------------------
// Kernel C2: d2 dots. 2000 blocks x 32 rows, 2-row ILP.
// ---------------------------------------------------------------------------
__global__ __launch_bounds__(256) void readout_dots(
    const unsigned long long* __restrict__ spk,  // [M_, 16]
    const float* __restrict__ W2,                // [O_, H_]
    float* __restrict__ d2t)                     // idx o*M_ + ts*256 + b
{
    const int t = threadIdx.x, wave = t >> 6, lane = t & 63;

    float w2r[5][16];
#pragma unroll
    for (int oo = 0; oo < 5; ++oo)
#pragma unroll
        for (int q = 0; q < 4; ++q)
            *(float4*)&w2r[oo][4 * q] =
                *(const float4*)&W2[(wave * 5 + oo) * H_ + lane * 16 + 4 * q];

    const int rbase = blockIdx.x * 32;           // M_ = 2000*32
    int b0 = rbase / T_;
    int ts0 = rbase - b0 * T_;

    for (int i = 0; i < 32; i += 2) {
        int r0 = rbase + i, r1 = r0 + 1;
        unsigned long long bw0 = spk[(long)r0 * 16 + (lane >> 2)];
        unsigned long long bw1 = spk[(long)r1 * 16 + (lane >> 2)];
        unsigned int bits0 = (unsigned int)(bw0 >> ((lane & 3) * 16)) & 0xFFFFu;
        unsigned int bits1 = (unsigned int)(bw1 >> ((lane & 3) * 16)) & 0xFFFFu;
        float pa0[5] = {0, 0, 0, 0, 0}, pa1[5] = {0, 0, 0, 0, 0};
#pragma unroll
        for (int j = 0; j < 16; ++j) {
            float f0 = (bits0 >> j) & 1u ? 1.0f : 0.0f;
            float f1 = (bits1 >> j) & 1u ? 1.0f : 0.0f;
#pragma unroll
            for (int oo = 0; oo < 5; ++oo) {
                pa0[oo] = fmaf(f0, w2r[oo][j], pa0[oo]);
                pa1[oo] = fmaf(f1, w2r[oo][j], pa1[oo]);
            }
        }
#pragma unroll
        for (int m = 1; m < 64; m <<= 1)
#pragma unroll
            for (int oo = 0; oo < 5; ++oo) {
                pa0[oo] += __shfl_xor(pa0[oo], m, 64);
                pa1[oo] += __shfl_xor(pa1[oo], m, 64);
            }
        if (lane == 0) {
            int bA = b0, tsA = ts0 + i;
            if (tsA >= T_) { tsA -= T_; bA += 1; }   // rbase%2==0, i even: safe
            int bB = bA, tsB = tsA + 1;
            if (tsB >= T_) { tsB = 0; bB += 1; }
#pragma unroll
            for (int oo = 0; oo < 5; ++oo) {
                d2t[(long)(wave * 5 + oo) * M_ + tsA * 256 + bA] = pa0[oo];
                d2t[(long)(wave * 5 + oo) * M_ + tsB * 256 + bB] = pa1[oo];
            }
        }
    }
}

// ---------------------------------------------------------------------------
// Kernel C3: mem2 linear recurrence. grid (20 o x 4 b-chunks), 64 threads.
// ---------------------------------------------------------------------------
__global__ __launch_bounds__(64) void mem2_scan(
    const float* __restrict__ d2t,   // (o, ts, b)
    const float* __restrict__ tau2, const float* __restrict__ b2,
    float* __restrict__ m2t)         // (o, ts, b)
{
    const int o = blockIdx.x;                    // 0..19
    const int b = blockIdx.y * 64 + threadIdx.x; // 0..255
    float tv  = tau2[o];
    float a2  = 1.0f / (1.0f + __expf(-tv));
    float om2 = 1.0f - a2;
    float bv  = b2[o];

    const float* dp = d2t + (long)o * M_ + b;
    float*       mp = m2t + (long)o * M_ + b;
    float mem = 0.f;

    float p0 = dp[0], p1 = dp[256], p2 = dp[512], p3 = dp[768];
    for (int ts = 0; ts < T_; ++ts) {
        float cur = p0; p0 = p1; p1 = p2; p2 = p3;
        int nts = ts + 4; nts = (nts < T_) ? nts : (T_ - 1);
        p3 = dp[(long)nts * 256];
        mem = mem * a2 + om2 * (cur + bv);
        mp[(long)ts * 256] = mem;
    }
}

// ---------------------------------------------------------------------------
// Kernel C4: per-(b,ts) softmax in-register + per-b sum over ts via LDS.
// ---------------------------------------------------------------------------
__global__ __launch_bounds__(256) void softmax_acc(
    const float* __restrict__ m2t,   // (o, ts, b)
    float* __restrict__ out)         // [B_, O_]
{
    __shared__ float sp[T_][O_];     // 19.5 KB
    const int b  = blockIdx.x;
    const int ts = threadIdx.x;

    if (ts < T_) {
        if (ts > 10) {
            float m[O_];
#pragma unroll
            for (int o = 0; o < O_; ++o)
                m[o] = m2t[(long)o * M_ + ts * 256 + b];
            float mx = m[0];
#pragma unroll
            for (int o = 1; o < O_; ++o) mx = fmaxf(mx, m[o]);
            float s = 0.f;
#pragma unroll
            for (int o = 0; o < O_; ++o) { m[o] = __expf(m[o] - mx); s += m[o]; }
            float inv = 1.0f / s;
#pragma unroll
            for (int o = 0; o < O_; ++o) sp[ts][o] = m[o] * inv;
        } else {
#pragma unroll
            for (int o = 0; o < O_; ++o) sp[ts][o] = 0.f;
        }
    }
    __syncthreads();
    if (ts < O_) {
        float s = 0.f;
        for (int k = 11; k < T_; ++k) s += sp[k][ts];
        out[b * O_ + ts] = s;
    }
}

// ---------------------------------------------------------------------------
extern "C" void kernel_launch(void* const* d_in, const int* in_sizes, int n_in,
                              void* d_out, int out_size, void* d_ws, size_t ws_size,
                              hipStream_t stream)
{
    const float* X    = (const float*)d_in[0];
    const float* W1   = (const float*)d_in[1];
    const float* b1   = (const float*)d_in[2];
    const float* tau1 = (const float*)d_in[3];
    const float* W2   = (const float*)d_in[4];
    const float* b2   = (const float*)d_in[5];
    const float* tau2 = (const float*)d_in[6];
    float* out = (float*)d_out;

    unsigned short* Xhi  = (unsigned short*)d_ws;
    unsigned short* Xlo  = Xhi + (long)M_ * KP;
    unsigned short* W1hi = Xlo + (long)M_ * KP;
    unsigned short* W1lo = W1hi + (long)H_ * KP;
    float* d1 = (float*)(W1lo + (long)H_ * KP);  // [M_, H] fp32

    unsigned long long* spk = (unsigned long long*)Xhi;      // aliases X splits
    float* d2t = (float*)Xlo;                                // (safe: sequential)
    float* m2t = d2t + (long)O_ * M_;

    // 1. split conversions
    {
        int chunks = M_ * (KP / 8);
        split_convert<<<(chunks + 255) / 256, 256, 0, stream>>>(X, Xhi, Xlo, M_, D_, KP);
    }
    {
        int chunks = H_ * (KP / 8);
        split_convert<<<(chunks + 255) / 256, 256, 0, stream>>>(W1, W1hi, W1lo, H_, D_, KP);
    }

    // 2. d1 = X @ W1^T + b1  (256^2 tile, 1000 blocks = 250 m x 4 n)
    gemm256<<<dim3(1000), dim3(512), 0, stream>>>(Xhi, Xlo, W1hi, W1lo, b1, d1);

    // 3. layer-1 spike scan
    {
        dim3 grid(H_ / 256, B_);                 // (4, 256)
        lif_spikes<<<grid, 256, 0, stream>>>(d1, tau1, spk);
    }

    // 4. readout dots
    readout_dots<<<M_ / 32, 256, 0, stream>>>(spk, W2, d2t);

    // 5. mem2 linear scan
    {
        dim3 grid(O_, 4);
        mem2_scan<<<grid, 64, 0, stream>>>(d2t, tau2, b2, m2t);
    }

    // 6. softmax + accumulate
    softmax_acc<<<B_, 256, 0, stream>>>(m2t, out);
}